// Round 3
// baseline (121900.598 us; speedup 1.0000x reference)
//
#include <hip/hip_runtime.h>
#include <cstdint>
#include <cstddef>

// Problem constants. Inputs/outputs are fp32 (established round 2: NaN under
// bf16 reads + error-4.15 signature of u16 writes into a float buffer).
constexpr int T_STEPS = 16384;
constexpr int D = 1024;
constexpr int G_WG = 64;    // recurrence workgroups (== lanes polling flags)
constexpr int C_COLS = 16;  // hidden columns owned per WG (G_WG * C_COLS == D)
constexpr int FLAG_STRIDE = 16;  // 64B per flag: no cache-line ping-pong

typedef __attribute__((ext_vector_type(8))) short bf16x8;
typedef __attribute__((ext_vector_type(4))) float f32x4;

// Device-global sync scratch (no dependence on ws_size). Flags re-zeroed
// every launch by init_flags; g_hbuf parity slots are always written before
// read within a launch, so stale contents are harmless.
__device__ int g_flags[G_WG * FLAG_STRIDE];
__device__ float g_hbuf[2 * D];

static __device__ __forceinline__ unsigned short f2bf(float f) {
  union { float f; unsigned int u; } v;
  v.f = f;
  unsigned int u = v.u;
  unsigned int r = (u + 0x7fffu + ((u >> 16) & 1u)) >> 16;  // RTN-even
  return (unsigned short)r;
}

__global__ void init_flags() {
  const int tid = threadIdx.x;
  for (int i = tid; i < G_WG * FLAG_STRIDE; i += 256) g_flags[i] = 0;
}

// ---------------------------------------------------------------------------
// GEMM: out[M][N] = A[M][K] @ B[K][N] + bias[N]; fp32 in/out, bf16 MFMA with
// fp32 accumulate. Tile 64x64, BK=32, 256 threads = 4 waves; wave w owns rows
// [16w,16w+16) via 4x mfma_f32_16x16x32_bf16 per K-step.
// ---------------------------------------------------------------------------
__global__ __launch_bounds__(256, 2) void gemm_bias(
    const float* __restrict__ A, const float* __restrict__ B,
    const float* __restrict__ bias, float* __restrict__ out, int M, int N,
    int K) {
  const int tid = threadIdx.x;
  const int wave = tid >> 6;
  const int lane = tid & 63;
  const int lrow = lane & 15;
  const int quad = lane >> 4;
  const int m0 = blockIdx.x * 64;
  const int n0 = blockIdx.y * 64;

  __shared__ __align__(16) unsigned short sA[64][40];  // stride 80B
  __shared__ __align__(16) unsigned short sB[32][68];  // stride 136B

  f32x4 acc[4];
#pragma unroll
  for (int s = 0; s < 4; ++s) acc[s] = (f32x4){0.f, 0.f, 0.f, 0.f};

  const int ar = tid >> 2;        // A stage row 0..63
  const int ac = (tid & 3) * 8;   // A stage col 0,8,16,24
  const int br = tid >> 3;        // B stage row 0..31
  const int bc = (tid & 7) * 8;   // B stage col 0..56

  for (int k0 = 0; k0 < K; k0 += 32) {
    union { unsigned short u[8]; uint4 v; } apk, bpk;
    {
      const float4 a0 = *(const float4*)(A + (size_t)(m0 + ar) * K + k0 + ac);
      const float4 a1 = *(const float4*)(A + (size_t)(m0 + ar) * K + k0 + ac + 4);
      apk.u[0] = f2bf(a0.x); apk.u[1] = f2bf(a0.y);
      apk.u[2] = f2bf(a0.z); apk.u[3] = f2bf(a0.w);
      apk.u[4] = f2bf(a1.x); apk.u[5] = f2bf(a1.y);
      apk.u[6] = f2bf(a1.z); apk.u[7] = f2bf(a1.w);
      const float4 b0 = *(const float4*)(B + (size_t)(k0 + br) * N + n0 + bc);
      const float4 b1 = *(const float4*)(B + (size_t)(k0 + br) * N + n0 + bc + 4);
      bpk.u[0] = f2bf(b0.x); bpk.u[1] = f2bf(b0.y);
      bpk.u[2] = f2bf(b0.z); bpk.u[3] = f2bf(b0.w);
      bpk.u[4] = f2bf(b1.x); bpk.u[5] = f2bf(b1.y);
      bpk.u[6] = f2bf(b1.z); bpk.u[7] = f2bf(b1.w);
    }

    __syncthreads();  // previous iteration's frag reads done
    *(uint4*)&sA[ar][ac] = apk.v;
    *(uint2*)&sB[br][bc] = make_uint2(bpk.v.x, bpk.v.y);
    *(uint2*)&sB[br][bc + 4] = make_uint2(bpk.v.z, bpk.v.w);
    __syncthreads();

    // A fragment: lane holds A[m=16w+lrow][k0 + quad*8 .. +8) (b128 read)
    bf16x8 afrag = *(const bf16x8*)&sA[16 * wave + lrow][quad * 8];
#pragma unroll
    for (int s = 0; s < 4; ++s) {
      bf16x8 bfrag;
#pragma unroll
      for (int jj = 0; jj < 8; ++jj)
        bfrag[jj] = (short)sB[quad * 8 + jj][s * 16 + lrow];
      acc[s] = __builtin_amdgcn_mfma_f32_16x16x32_bf16(afrag, bfrag, acc[s], 0, 0, 0);
    }
  }

// epilogue: C/D layout col = lane&15, row = quad*4 + reg (m89-verified)
#pragma unroll
  for (int s = 0; s < 4; ++s) {
    const int col = n0 + s * 16 + lrow;
    const float bsv = bias[col];
#pragma unroll
    for (int r = 0; r < 4; ++r) {
      const int row = m0 + 16 * wave + quad * 4 + r;
      out[(size_t)row * N + col] = acc[s][r] + bsv;
    }
  }
}

// ---------------------------------------------------------------------------
// Recurrence: h_t = tanh(Apre[t] + h_{t-1} @ Wh), Hout[t] = h_t (fp32).
// 64 WGs x 256 threads, co-resident by capacity (64 blocks <= 256 CUs at
// 1 block/CU). WG g owns cols [16g,16g+16) of Wh in VGPRs (64 fp32/thread).
// Per step: local matvec -> shuffle+LDS reduce -> tanh -> publish 16 floats +
// release flag -> poll 64 flags (relaxed; one fence after) -> pull h to LDS.
// Double-buffered g_hbuf parity + per-step all-flags gate => distance-2 safety.
// ---------------------------------------------------------------------------
__global__ __launch_bounds__(256, 1) void rnn_recur(
    const float* __restrict__ Apre, const float* __restrict__ Wh,
    float* __restrict__ Hout) {
  const int g = blockIdx.x;
  const int tid = threadIdx.x;
  const int j = tid & 15;   // column within WG slice
  const int rc = tid >> 4;  // row-chunk 0..15 (64 rows each)
  const int col = g * C_COLS + j;
  const int wave = tid >> 6;
  const int lane = tid & 63;

  // Wh slice into registers (full unroll => static indices => VGPRs)
  float W[64];
#pragma unroll
  for (int kk = 0; kk < 64; ++kk)
    W[kk] = Wh[(size_t)(rc * 64 + kk) * D + col];

  __shared__ float hl[D];
  __shared__ float red[64];
  __shared__ int sdead;
  if (tid == 0) sdead = 0;
  for (int i = tid; i < D; i += 256) hl[i] = 0.f;  // h_{-1} = 0
  __syncthreads();

  float acur = Apre[col];  // A row for t=0
  int dead = 0;

  for (int t = 0; t < T_STEPS; ++t) {
    // prefetch next A row (hidden behind this step's compute+sync)
    float anext = 0.f;
    if (t + 1 < T_STEPS) anext = Apre[(size_t)(t + 1) * D + col];

    // partial dot over this thread's 64-row chunk
    float accv = 0.f;
    const float4* hv = (const float4*)&hl[rc * 64];
#pragma unroll
    for (int kk = 0; kk < 16; ++kk) {
      float4 h4 = hv[kk];
      accv = fmaf(W[4 * kk + 0], h4.x, accv);
      accv = fmaf(W[4 * kk + 1], h4.y, accv);
      accv = fmaf(W[4 * kk + 2], h4.z, accv);
      accv = fmaf(W[4 * kk + 3], h4.w, accv);
    }
    // reduce rc within wave: lanes L, L^16, L^32, L^48 share j
    accv += __shfl_xor(accv, 16);
    accv += __shfl_xor(accv, 32);
    if (lane < 16) red[wave * 16 + lane] = accv;
    __syncthreads();

    if (tid < 16) {
      float pre = acur + red[j] + red[16 + j] + red[32 + j] + red[48 + j];
      pre = fminf(fmaxf(pre, -30.f), 30.f);  // scrub any non-finite
      float h = tanhf(pre);
      Hout[(size_t)t * D + col] = h;
      __hip_atomic_store(&g_hbuf[(t & 1) * D + col], h, __ATOMIC_RELAXED,
                         __HIP_MEMORY_SCOPE_AGENT);
    }
    if (tid == 0) {
      __threadfence();  // wave-level vmcnt drain covers lanes 0..15's stores
      __hip_atomic_store(&g_flags[g * FLAG_STRIDE], t + 1, __ATOMIC_RELEASE,
                         __HIP_MEMORY_SCOPE_AGENT);
    }

    acur = anext;
    if (t + 1 == T_STEPS) break;

    // wait for all 64 WGs to publish step t (lane l polls WG l's flag)
    if (!dead) {
      int spins = 0;
      for (;;) {
        int v = __hip_atomic_load(&g_flags[lane * FLAG_STRIDE],
                                  __ATOMIC_RELAXED, __HIP_MEMORY_SCOPE_AGENT);
        if (__all(v >= t + 1)) break;
        __builtin_amdgcn_s_sleep(1);
        if (++spins > (1 << 17)) { sdead = 1; break; }  // bailout: no hang
      }
      __threadfence();  // acquire: make published h visible
    }

    // pull full h_t into LDS (4 floats/thread)
    {
      const int base = (t & 1) * D + tid * 4;
      float v0 = __hip_atomic_load(&g_hbuf[base + 0], __ATOMIC_RELAXED,
                                   __HIP_MEMORY_SCOPE_AGENT);
      float v1 = __hip_atomic_load(&g_hbuf[base + 1], __ATOMIC_RELAXED,
                                   __HIP_MEMORY_SCOPE_AGENT);
      float v2 = __hip_atomic_load(&g_hbuf[base + 2], __ATOMIC_RELAXED,
                                   __HIP_MEMORY_SCOPE_AGENT);
      float v3 = __hip_atomic_load(&g_hbuf[base + 3], __ATOMIC_RELAXED,
                                   __HIP_MEMORY_SCOPE_AGENT);
      hl[tid * 4 + 0] = v0;
      hl[tid * 4 + 1] = v1;
      hl[tid * 4 + 2] = v2;
      hl[tid * 4 + 3] = v3;
    }
    __syncthreads();
    dead |= sdead;
  }
}

// ---------------------------------------------------------------------------
extern "C" void kernel_launch(void* const* d_in, const int* in_sizes, int n_in,
                              void* d_out, int out_size, void* d_ws,
                              size_t ws_size, hipStream_t stream) {
  const float* X  = (const float*)d_in[0];  // [T][D]
  const float* Wx = (const float*)d_in[1];  // [D][D]
  const float* Wh = (const float*)d_in[2];  // [D][D]
  const float* Wy = (const float*)d_in[3];  // [D][D]
  const float* bh = (const float*)d_in[4];  // [D]
  const float* by = (const float*)d_in[5];  // [D]

  float* Hout = (float*)d_out;              // hidden [T][D] fp32
  float* Yout = Hout + (size_t)T_STEPS * D; // outputs [T][D] fp32
  float* Apre = Yout;  // pre-activation scratch; exactly T*D floats,
                       // overwritten by Y in phase 3 (after recurrence reads it)

  const dim3 ggrid(T_STEPS / 64, D / 64);

  init_flags<<<dim3(1), dim3(256), 0, stream>>>();

  // Phase 1: Apre = X @ Wx + bh
  gemm_bias<<<ggrid, dim3(256), 0, stream>>>(X, Wx, bh, Apre, T_STEPS, D, D);

  // Phase 2: sequential recurrence (64 co-resident WGs; flag-based sync)
  rnn_recur<<<dim3(G_WG), dim3(256), 0, stream>>>(Apre, Wh, Hout);

  // Phase 3: Y = H @ Wy + by (overwrites Apre region)
  gemm_bias<<<ggrid, dim3(256), 0, stream>>>(Hout, Wy, by, Yout, T_STEPS, D, D);
}

// Round 4
// 39307.397 us; speedup vs baseline: 3.1012x; 3.1012x over previous
//
#include <hip/hip_runtime.h>
#include <cstdint>
#include <cstddef>

// Problem constants. Inputs/outputs are fp32 (established rounds 1-2).
constexpr int T_STEPS = 16384;
constexpr int D = 1024;
constexpr int G_WG = 64;    // recurrence workgroups
constexpr int C_COLS = 16;  // hidden columns owned per WG (G_WG * C_COLS == D)

typedef __attribute__((ext_vector_type(8))) short bf16x8;
typedef __attribute__((ext_vector_type(4))) float f32x4;

// Published hidden state: self-validating (tag<<32 | f32bits) words, double-
// buffered by step parity. Relaxed agent-scope atomics only — NO fences, so
// no buffer_wbl2/buffer_inv L2 nukes on the critical path (round-3 lesson:
// __threadfence() per step caused 766MB overfetch and ~9us/step).
__device__ unsigned long long g_hpub[2 * D];

static __device__ __forceinline__ unsigned short f2bf(float f) {
  union { float f; unsigned int u; } v;
  v.f = f;
  unsigned int u = v.u;
  unsigned int r = (u + 0x7fffu + ((u >> 16) & 1u)) >> 16;  // RTN-even
  return (unsigned short)r;
}
static __device__ __forceinline__ unsigned int f_as_u(float f) {
  union { float f; unsigned int u; } v; v.f = f; return v.u;
}
static __device__ __forceinline__ float u_as_f(unsigned int u) {
  union { unsigned int u; float f; } v; v.u = u; return v.f;
}

__global__ void init_hpub() {
  const int i = blockIdx.x * 256 + threadIdx.x;
  if (i < 2 * D) g_hpub[i] = 0ull;  // tag 0 => never matches wanted tag >= 1
}

// ---------------------------------------------------------------------------
// GEMM: out[M][N] = A[M][K] @ B[K][N] + bias[N]; fp32 in/out, bf16 MFMA with
// fp32 accumulate. Tile 64x64, BK=32, 256 threads = 4 waves.
// ---------------------------------------------------------------------------
__global__ __launch_bounds__(256, 2) void gemm_bias(
    const float* __restrict__ A, const float* __restrict__ B,
    const float* __restrict__ bias, float* __restrict__ out, int M, int N,
    int K) {
  const int tid = threadIdx.x;
  const int wave = tid >> 6;
  const int lane = tid & 63;
  const int lrow = lane & 15;
  const int quad = lane >> 4;
  const int m0 = blockIdx.x * 64;
  const int n0 = blockIdx.y * 64;

  __shared__ __align__(16) unsigned short sA[64][40];  // stride 80B
  __shared__ __align__(16) unsigned short sB[32][68];  // stride 136B

  f32x4 acc[4];
#pragma unroll
  for (int s = 0; s < 4; ++s) acc[s] = (f32x4){0.f, 0.f, 0.f, 0.f};

  const int ar = tid >> 2;        // A stage row 0..63
  const int ac = (tid & 3) * 8;   // A stage col 0,8,16,24
  const int br = tid >> 3;        // B stage row 0..31
  const int bc = (tid & 7) * 8;   // B stage col 0..56

  for (int k0 = 0; k0 < K; k0 += 32) {
    union { unsigned short u[8]; uint4 v; } apk, bpk;
    {
      const float4 a0 = *(const float4*)(A + (size_t)(m0 + ar) * K + k0 + ac);
      const float4 a1 = *(const float4*)(A + (size_t)(m0 + ar) * K + k0 + ac + 4);
      apk.u[0] = f2bf(a0.x); apk.u[1] = f2bf(a0.y);
      apk.u[2] = f2bf(a0.z); apk.u[3] = f2bf(a0.w);
      apk.u[4] = f2bf(a1.x); apk.u[5] = f2bf(a1.y);
      apk.u[6] = f2bf(a1.z); apk.u[7] = f2bf(a1.w);
      const float4 b0 = *(const float4*)(B + (size_t)(k0 + br) * N + n0 + bc);
      const float4 b1 = *(const float4*)(B + (size_t)(k0 + br) * N + n0 + bc + 4);
      bpk.u[0] = f2bf(b0.x); bpk.u[1] = f2bf(b0.y);
      bpk.u[2] = f2bf(b0.z); bpk.u[3] = f2bf(b0.w);
      bpk.u[4] = f2bf(b1.x); bpk.u[5] = f2bf(b1.y);
      bpk.u[6] = f2bf(b1.z); bpk.u[7] = f2bf(b1.w);
    }

    __syncthreads();  // previous iteration's frag reads done
    *(uint4*)&sA[ar][ac] = apk.v;
    *(uint2*)&sB[br][bc] = make_uint2(bpk.v.x, bpk.v.y);
    *(uint2*)&sB[br][bc + 4] = make_uint2(bpk.v.z, bpk.v.w);
    __syncthreads();

    bf16x8 afrag = *(const bf16x8*)&sA[16 * wave + lrow][quad * 8];
#pragma unroll
    for (int s = 0; s < 4; ++s) {
      bf16x8 bfrag;
#pragma unroll
      for (int jj = 0; jj < 8; ++jj)
        bfrag[jj] = (short)sB[quad * 8 + jj][s * 16 + lrow];
      acc[s] = __builtin_amdgcn_mfma_f32_16x16x32_bf16(afrag, bfrag, acc[s], 0, 0, 0);
    }
  }

// epilogue: C/D layout col = lane&15, row = quad*4 + reg (m89-verified)
#pragma unroll
  for (int s = 0; s < 4; ++s) {
    const int col = n0 + s * 16 + lrow;
    const float bsv = bias[col];
#pragma unroll
    for (int r = 0; r < 4; ++r) {
      const int row = m0 + 16 * wave + quad * 4 + r;
      out[(size_t)row * N + col] = acc[s][r] + bsv;
    }
  }
}

// ---------------------------------------------------------------------------
// Recurrence: h_t = tanh(Apre[t] + h_{t-1} @ Wh), Hout[t] = h_t (fp32).
// 64 WGs x 256 threads, co-resident by capacity (64 blocks <= 256 CUs at
// 1 block/CU). WG g owns cols [16g,16g+16) of Wh in VGPRs (64 fp32/thread).
// Per step: matvec -> shuffle+LDS reduce -> tanh -> publish 16 tagged u64s
// (relaxed) -> poll all 1024 tagged words (relaxed, 4/thread) into LDS.
// Parity double-buffer + publish-after-full-read ordering => distance-2 safe.
// ---------------------------------------------------------------------------
__global__ __launch_bounds__(256, 1) void rnn_recur(
    const float* __restrict__ Apre, const float* __restrict__ Wh,
    float* __restrict__ Hout) {
  const int g = blockIdx.x;
  const int tid = threadIdx.x;
  const int j = tid & 15;   // column within WG slice
  const int rc = tid >> 4;  // row-chunk 0..15 (64 rows each)
  const int col = g * C_COLS + j;
  const int wave = tid >> 6;
  const int lane = tid & 63;

  // Wh slice into registers (full unroll => static indices => VGPRs)
  float W[64];
#pragma unroll
  for (int kk = 0; kk < 64; ++kk)
    W[kk] = Wh[(size_t)(rc * 64 + kk) * D + col];

  __shared__ float hl[D];
  __shared__ int sdead;
  __shared__ float red[64];
  if (tid == 0) sdead = 0;
  for (int i = tid; i < D; i += 256) hl[i] = 0.f;  // h_{-1} = 0
  __syncthreads();

  float acur = Apre[col];  // A row for t=0
  int dead = 0;

  for (int t = 0; t < T_STEPS; ++t) {
    // prefetch next A row (hidden behind this step's compute+sync)
    float anext = 0.f;
    if (t + 1 < T_STEPS) anext = Apre[(size_t)(t + 1) * D + col];

    // partial dot over this thread's 64-row chunk
    float accv = 0.f;
    const float4* hv = (const float4*)&hl[rc * 64];
#pragma unroll
    for (int kk = 0; kk < 16; ++kk) {
      float4 h4 = hv[kk];
      accv = fmaf(W[4 * kk + 0], h4.x, accv);
      accv = fmaf(W[4 * kk + 1], h4.y, accv);
      accv = fmaf(W[4 * kk + 2], h4.z, accv);
      accv = fmaf(W[4 * kk + 3], h4.w, accv);
    }
    // reduce rc within wave: lanes L, L^16, L^32, L^48 share j
    accv += __shfl_xor(accv, 16);
    accv += __shfl_xor(accv, 32);
    if (lane < 16) red[wave * 16 + lane] = accv;
    __syncthreads();

    if (tid < 16) {
      float pre = acur + red[j] + red[16 + j] + red[32 + j] + red[48 + j];
      pre = fminf(fmaxf(pre, -30.f), 30.f);  // scrub any non-finite
      float h = tanhf(pre);
      Hout[(size_t)t * D + col] = h;
      const unsigned long long pk =
          ((unsigned long long)(unsigned)(t + 1) << 32) |
          (unsigned long long)f_as_u(h);
      __hip_atomic_store(&g_hpub[(t & 1) * D + col], pk, __ATOMIC_RELAXED,
                         __HIP_MEMORY_SCOPE_AGENT);
    }

    acur = anext;
    if (t + 1 == T_STEPS) break;

    // pull full h_t: poll 4 tagged words per thread until tag == t+1
    if (!dead) {
      const unsigned int want = (unsigned)(t + 1);
      const int base = (t & 1) * D + tid * 4;
      int pend = 0xF;
      int spins = 0;
      do {
#pragma unroll
        for (int q = 0; q < 4; ++q) {
          if (pend & (1 << q)) {
            unsigned long long w = __hip_atomic_load(
                &g_hpub[base + q], __ATOMIC_RELAXED, __HIP_MEMORY_SCOPE_AGENT);
            if ((unsigned)(w >> 32) == want) {
              hl[tid * 4 + q] = u_as_f((unsigned)w);
              pend &= ~(1 << q);
            }
          }
        }
        if (!pend) break;
        if ((++spins & 7) == 7) __builtin_amdgcn_s_sleep(1);
        if (spins > (1 << 20)) { sdead = 1; break; }  // bailout: no hang
      } while (true);
    }
    __syncthreads();
    dead |= sdead;
  }
}

// ---------------------------------------------------------------------------
extern "C" void kernel_launch(void* const* d_in, const int* in_sizes, int n_in,
                              void* d_out, int out_size, void* d_ws,
                              size_t ws_size, hipStream_t stream) {
  const float* X  = (const float*)d_in[0];  // [T][D]
  const float* Wx = (const float*)d_in[1];  // [D][D]
  const float* Wh = (const float*)d_in[2];  // [D][D]
  const float* Wy = (const float*)d_in[3];  // [D][D]
  const float* bh = (const float*)d_in[4];  // [D]
  const float* by = (const float*)d_in[5];  // [D]

  float* Hout = (float*)d_out;              // hidden [T][D] fp32
  float* Yout = Hout + (size_t)T_STEPS * D; // outputs [T][D] fp32
  float* Apre = Yout;  // pre-activation scratch; overwritten by Y in phase 3

  const dim3 ggrid(T_STEPS / 64, D / 64);

  init_hpub<<<dim3((2 * D + 255) / 256), dim3(256), 0, stream>>>();

  // Phase 1: Apre = X @ Wx + bh
  gemm_bias<<<ggrid, dim3(256), 0, stream>>>(X, Wx, bh, Apre, T_STEPS, D, D);

  // Phase 2: sequential recurrence (64 co-resident WGs; tagged-word sync)
  rnn_recur<<<dim3(G_WG), dim3(256), 0, stream>>>(Apre, Wh, Hout);

  // Phase 3: Y = H @ Wy + by (overwrites Apre region)
  gemm_bias<<<ggrid, dim3(256), 0, stream>>>(Hout, Wy, by, Yout, T_STEPS, D, D);
}